// Round 9
// baseline (158.403 us; speedup 1.0000x reference)
//
#include <hip/hip_runtime.h>
#include <hip/hip_bf16.h>

#define NB 8
#define N1 2048
#define N2 1152
#define KD 1024
#define BM 128
#define BN 144
#define BNP 145    // padded epilogue stride
#define BUFB 17408 // one staging buffer: 17 chunks x 1 KB

typedef __attribute__((ext_vector_type(4))) float f32x4;
typedef __attribute__((ext_vector_type(2))) long i64x2;

__device__ __forceinline__ unsigned pack4_fp8(f32x4 v) {
  int t = __builtin_amdgcn_cvt_pk_fp8_f32(v.x, v.y, 0, false);
  t = __builtin_amdgcn_cvt_pk_fp8_f32(v.z, v.w, t, true);
  return (unsigned)t;
}

// One WAVE per row. XCD-aligned: bid&7 = batch, so batch b's rows convert on
// XCD b and the fp8 writes (3.3 MB/batch) stay hot in that XCD's 4 MB L2 for
// dist_kernel (R8: dist FETCH_SIZE 12.9 MB vs 26 MB compulsory — verified).
// Source fp32 reads NONTEMPORAL so the stream doesn't evict the fp8 lines.
// fp8 pack + k-block permutation staged through LDS, written out as coalesced
// uint4. Permuted layout per 64-value k-block: 16B group q holds
// k=[q*8..q*8+7] ++ [32+q*8..32+q*8+7] -> one b128 LDS read = both k-half
// MFMA fragments.
__global__ __launch_bounds__(256) void convert_kernel(
    const float* __restrict__ x1, const float* __restrict__ x2,
    unsigned char* __restrict__ x1q, unsigned char* __restrict__ x2q,
    float* __restrict__ sq1, float* __restrict__ sq2) {
  __shared__ __align__(16) unsigned char lds[4096];
  int wave = threadIdx.x >> 6, lane = threadIdx.x & 63;
  int bid = blockIdx.x;
  int b = bid & 7;          // batch -> XCD
  int idx = bid >> 3;       // 0..799 within batch
  const float* src;
  unsigned char* dst;
  float* sqp;
  if (idx < N1 / 4) {
    int row = b * N1 + idx * 4 + wave;
    src = x1 + (size_t)row * KD;
    dst = x1q + (size_t)row * KD;
    sqp = sq1 + row;
  } else {
    int row = b * N2 + (idx - N1 / 4) * 4 + wave;
    src = x2 + (size_t)row * KD;
    dst = x2q + (size_t)row * KD;
    sqp = sq2 + row;
  }
  const f32x4* s4 = (const f32x4*)src;
  int r = 4 * (lane & 15);
  int q = (r & 31) >> 3;
  int h = r >> 5;
  int pos = (lane >> 4) * 64 + q * 16 + h * 8 + (r & 7);
  unsigned char* my = lds + wave * 1024;
  float s = 0.f;
#pragma unroll
  for (int i = 0; i < 4; ++i) {
    f32x4 v = __builtin_nontemporal_load(&s4[i * 64 + lane]);
    *(unsigned*)(my + i * 256 + pos) = pack4_fp8(v);
    s += v.x * v.x + v.y * v.y + v.z * v.z + v.w * v.w;
  }
  __syncthreads();  // cross-lane LDS visibility
  ((uint4*)dst)[lane] = *(const uint4*)(my + lane * 16);
#pragma unroll
  for (int off = 32; off > 0; off >>= 1) s += __shfl_down(s, off);
  if (lane == 0) *sqp = s;
}

__device__ __forceinline__ void async_copy16(const void* g, void* l) {
  __builtin_amdgcn_global_load_lds(
      (const __attribute__((address_space(1))) unsigned int*)g,
      (__attribute__((address_space(3))) unsigned int*)l, 16, 0, 0);
}

// Fused fp8 distance + group-min(9) + mean — DOUBLE-BUFFERED K-loop.
// R8 analysis: ~900 of ~1630 cyc/iter was the vmcnt(0)+s_barrier drain of
// just-issued global_load_lds (m97-structure stall). fp8 staging is small
// enough (17.4 KB) that TWO buffers fit (34.8 KB <= 37.1 KB epilogue union),
// so the K-loop becomes 1 barrier/iter:
//   barrier -> issue async stage into buf[nxt] -> compute from buf[cur]
// At the barrier the drain waits only on loads issued a full compute-phase
// (~700 cyc) earlier — L2 latency (~200-400) is covered. Both hazards
// (cur-ready, nxt read-before-overwrite) are covered by the same barrier.
// CRITICAL: every loop touching acc[][] must be FULLY UNROLLED — any runtime
// index defeats SROA and scratches the accumulators (R2-R4: 1.2 GB
// WRITE_SIZE, 3-10x slowdown). Tripwire: WRITE_SIZE must stay ~0.
// Grid 1D 1024: b = bid&7 -> batch b on XCD b; 3.3 MB working set < 4 MB L2,
// pre-warmed by convert_kernel on the same XCD (R8-verified).
// LDS chunks 1 KB = 16 rows x 64 fp8, XOR swizzle (slot ^ (row>>1)&3) ->
// conflict-free b128 fragment reads (verified R2-R8).
__global__ __launch_bounds__(256, 2) void dist_kernel(
    const unsigned char* __restrict__ x1q, const unsigned char* __restrict__ x2q,
    const float* __restrict__ sq1, const float* __restrict__ sq2,
    float* __restrict__ out) {
  __shared__ __align__(16) char smem[64 * BNP * 4];  // 37120 B >= 2*17408 staging

  const int tid = threadIdx.x;
  const int wave = tid >> 6, lane = tid & 63;
  const int bid = blockIdx.x;
  const int b = bid & 7;           // batch -> XCD
  const int bm = (bid >> 3) & 15;  // fastest: A streams, B-tile L2-hot
  const int bn = bid >> 7;

  const unsigned char* Ag = x1q + ((size_t)b * N1 + bm * BM) * KD;
  const unsigned char* Bg = x2q + ((size_t)b * N2 + bn * BN) * KD;

  // staging: lane -> (row lr, 16B slot sl), fetch the swizzled global group
  const int lr = lane >> 2, sl = lane & 3;
  const int goff = (sl ^ ((lr >> 1) & 3)) * 16;

  // fragments: lane (fr, quad) reads swizzled slot -> global 16B group `quad`
  const int quad = lane >> 4, fr = lane & 15;
  const int fslot = (fr * 4 + (quad ^ ((fr >> 1) & 3))) * 16;

  f32x4 acc[2][9];
#pragma unroll
  for (int i = 0; i < 2; ++i)
#pragma unroll
    for (int j = 0; j < 9; ++j) {
      f32x4 z = {0.f, 0.f, 0.f, 0.f};
      acc[i][j] = z;
    }

  // stage(k0) into buffer `buf`: 17 chunks (0..7 = A 128 rows, 8..16 = B 144)
  auto stage = [&](int buf, int k0) {
    char* base = smem + buf * BUFB;
    for (int j = wave; j < 17; j += 4) {
      const unsigned char* g;
      if (j < 8)
        g = Ag + (size_t)(j * 16 + lr) * KD + k0 + goff;
      else
        g = Bg + (size_t)((j - 8) * 16 + lr) * KD + k0 + goff;
      async_copy16(g, base + j * 1024 + lane * 16);
    }
  };

  stage(0, 0);  // prologue prefetch
  for (int i = 0; i < 16; ++i) {
    const int cur = i & 1;
    __syncthreads();  // drains cur's loads (issued a full iter ago) + guards nxt reuse
    if (i < 15) stage(cur ^ 1, (i + 1) * 64);
    const char* cb = smem + cur * BUFB;

    i64x2 a0 = *(const i64x2*)(cb + (wave * 2 + 0) * 1024 + fslot);
    i64x2 a1 = *(const i64x2*)(cb + (wave * 2 + 1) * 1024 + fslot);
#pragma unroll
    for (int tn = 0; tn < 9; ++tn) {
      i64x2 bf = *(const i64x2*)(cb + 8192 + tn * 1024 + fslot);
      acc[0][tn] = __builtin_amdgcn_mfma_f32_16x16x32_fp8_fp8(a0.x, bf.x, acc[0][tn], 0, 0, 0);
      acc[0][tn] = __builtin_amdgcn_mfma_f32_16x16x32_fp8_fp8(a0.y, bf.y, acc[0][tn], 0, 0, 0);
      acc[1][tn] = __builtin_amdgcn_mfma_f32_16x16x32_fp8_fp8(a1.x, bf.x, acc[1][tn], 0, 0, 0);
      acc[1][tn] = __builtin_amdgcn_mfma_f32_16x16x32_fp8_fp8(a1.y, bf.y, acc[1][tn], 0, 0, 0);
    }
  }

  // ---- epilogue: d = sq1 + sq2 - 2*cross, min over 9-col groups, sum ----
  float s2[9];
#pragma unroll
  for (int tn = 0; tn < 9; ++tn)
    s2[tn] = sq2[(size_t)b * N2 + bn * BN + tn * 16 + fr];

  float s1v[2][4];
#pragma unroll
  for (int tm = 0; tm < 2; ++tm)
#pragma unroll
    for (int r = 0; r < 4; ++r)
      s1v[tm][r] = sq1[(size_t)b * N1 + bm * BM + wave * 32 + tm * 16 + quad * 4 + r];

  float* eps = (float*)smem;
  float local = 0.f;
#pragma unroll  // FULL unroll: acc indices must be compile-time constants
  for (int tm = 0; tm < 2; ++tm) {
    __syncthreads();  // K-loop LDS / previous chunk fully consumed
    // D layout (16x16x32, dtype-independent): col = lane&15 (x2 row),
    // row = quad*4 + reg (x1 row). Chunk row = wave*16 + quad*4 + r.
#pragma unroll
    for (int tn = 0; tn < 9; ++tn)
#pragma unroll
      for (int r = 0; r < 4; ++r)
        eps[(wave * 16 + quad * 4 + r) * BNP + tn * 16 + fr] =
            s1v[tm][r] + s2[tn] - 2.0f * acc[tm][tn][r];
    __syncthreads();
    // 64 rows x 16 groups = 1024 groups, 4 per thread
#pragma unroll
    for (int qq = 0; qq < 4; ++qq) {
      int g = tid + qq * 256;
      int row = g >> 4, grp = g & 15;
      const float* p = eps + row * BNP + grp * 9;
      float mn = p[0];
#pragma unroll
      for (int jj = 1; jj < 9; ++jj) mn = fminf(mn, p[jj]);
      local += mn;
    }
  }

#pragma unroll
  for (int off = 32; off > 0; off >>= 1) local += __shfl_down(local, off);
  __syncthreads();
  if (lane == 0) eps[wave] = local;
  __syncthreads();
  if (tid == 0) {
    float s = eps[0] + eps[1] + eps[2] + eps[3];
    // total group count = 8 * 2048 * 1152 / 9 = 2097152
    atomicAdd(out, s * (1.0f / 2097152.0f));
  }
}

extern "C" void kernel_launch(void* const* d_in, const int* in_sizes, int n_in,
                              void* d_out, int out_size, void* d_ws, size_t ws_size,
                              hipStream_t stream) {
  const float* x1 = (const float*)d_in[0];
  const float* x2 = (const float*)d_in[1];
  char* ws = (char*)d_ws;
  const size_t x1q_bytes = (size_t)NB * N1 * KD;  // 16777216
  const size_t x2q_bytes = (size_t)NB * N2 * KD;  // 9437184
  unsigned char* x1q = (unsigned char*)ws;
  unsigned char* x2q = (unsigned char*)(ws + x1q_bytes);
  float* sq1 = (float*)(ws + x1q_bytes + x2q_bytes);
  float* sq2 = (float*)(ws + x1q_bytes + x2q_bytes + (size_t)NB * N1 * 4);

  (void)hipMemsetAsync(d_out, 0, sizeof(float), stream);
  convert_kernel<<<NB * (N1 / 4 + N2 / 4), 256, 0, stream>>>(x1, x2, x1q, x2q, sq1, sq2);
  dist_kernel<<<NB * (N1 / BM) * (N2 / BN), 256, 0, stream>>>(x1q, x2q, sq1, sq2,
                                                              (float*)d_out);
}

// Round 10
// 155.709 us; speedup vs baseline: 1.0173x; 1.0173x over previous
//
#include <hip/hip_runtime.h>
#include <hip/hip_bf16.h>

#define NB 8
#define N1 2048
#define N2 1152
#define KD 1024
#define BM 256
#define BN 144
#define BNP 145     // padded epilogue stride
#define BUFB 25600  // one staging buffer: 25 chunks x 1 KB (16 A + 9 B)

typedef __attribute__((ext_vector_type(4))) float f32x4;
typedef __attribute__((ext_vector_type(2))) long i64x2;

__device__ __forceinline__ unsigned pack4_fp8(f32x4 v) {
  int t = __builtin_amdgcn_cvt_pk_fp8_f32(v.x, v.y, 0, false);
  t = __builtin_amdgcn_cvt_pk_fp8_f32(v.z, v.w, t, true);
  return (unsigned)t;
}

// One WAVE per row. XCD-aligned: bid&7 = batch, so batch b's rows convert on
// XCD b and the fp8 writes (3.3 MB/batch) stay hot in that XCD's 4 MB L2 for
// dist_kernel (R8-verified: dist FETCH 12.9 MB vs 26 MB compulsory).
// Source fp32 reads NONTEMPORAL so the stream doesn't evict the fp8 lines.
// fp8 pack + k-block permutation staged through LDS, written out as coalesced
// uint4. Permuted layout per 64-value k-block: 16B group q holds
// k=[q*8..q*8+7] ++ [32+q*8..32+q*8+7] -> one b128 LDS read = both k-half
// MFMA fragments.
__global__ __launch_bounds__(256) void convert_kernel(
    const float* __restrict__ x1, const float* __restrict__ x2,
    unsigned char* __restrict__ x1q, unsigned char* __restrict__ x2q,
    float* __restrict__ sq1, float* __restrict__ sq2) {
  __shared__ __align__(16) unsigned char lds[4096];
  int wave = threadIdx.x >> 6, lane = threadIdx.x & 63;
  int bid = blockIdx.x;
  int b = bid & 7;          // batch -> XCD
  int idx = bid >> 3;       // 0..799 within batch
  const float* src;
  unsigned char* dst;
  float* sqp;
  if (idx < N1 / 4) {
    int row = b * N1 + idx * 4 + wave;
    src = x1 + (size_t)row * KD;
    dst = x1q + (size_t)row * KD;
    sqp = sq1 + row;
  } else {
    int row = b * N2 + (idx - N1 / 4) * 4 + wave;
    src = x2 + (size_t)row * KD;
    dst = x2q + (size_t)row * KD;
    sqp = sq2 + row;
  }
  const f32x4* s4 = (const f32x4*)src;
  int r = 4 * (lane & 15);
  int q = (r & 31) >> 3;
  int h = r >> 5;
  int pos = (lane >> 4) * 64 + q * 16 + h * 8 + (r & 7);
  unsigned char* my = lds + wave * 1024;
  float s = 0.f;
#pragma unroll
  for (int i = 0; i < 4; ++i) {
    f32x4 v = __builtin_nontemporal_load(&s4[i * 64 + lane]);
    *(unsigned*)(my + i * 256 + pos) = pack4_fp8(v);
    s += v.x * v.x + v.y * v.y + v.z * v.z + v.w * v.w;
  }
  __syncthreads();  // cross-lane LDS visibility
  ((uint4*)dst)[lane] = *(const uint4*)(my + lane * 16);
#pragma unroll
  for (int off = 32; off > 0; off >>= 1) s += __shfl_down(s, off);
  if (lane == 0) *sqp = s;
}

__device__ __forceinline__ void async_copy16(const void* g, void* l) {
  __builtin_amdgcn_global_load_lds(
      (const __attribute__((address_space(1))) unsigned int*)g,
      (__attribute__((address_space(3))) unsigned int*)l, 16, 0, 0);
}

// Fused fp8 distance + group-min(9) + mean — BM=256 + DOUBLE-BUFFER.
// R9 analysis: with the barrier drain mitigated by dbuf, the LDS pipe is the
// wall. Wave tile 4x9 (BM=256) raises FLOP/LDS-read-byte from 1.64 to 2.77
// and halves staging-write traffic per CU-iter (2 blocks/CU vs 4).
// Dbuf K-loop, 1 barrier/iter: barrier -> stage buf[nxt] -> compute buf[cur];
// at the barrier the vmcnt(0) drain waits on loads issued a full compute
// phase earlier (R9-validated structure, absmax 0).
// LDS: 2 x 25.6 KB staging, unioned with 37.1 KB epilogue -> 51.2 KB.
// CRITICAL: every loop touching acc[][] must be FULLY UNROLLED — any runtime
// index defeats SROA and scratches the accumulators (R2-R4: 1.2 GB
// WRITE_SIZE, 3-10x slowdown). Tripwire: WRITE_SIZE must stay ~32 B.
// Grid 1D 512: b = bid&7 -> batch b on XCD b (3.3 MB < 4 MB L2, pre-warmed
// by convert_kernel — R8-verified).
// LDS chunks 1 KB = 16 rows x 64 fp8, XOR swizzle (slot ^ (row>>1)&3) ->
// conflict-free b128 fragment reads (verified R2-R9).
__global__ __launch_bounds__(256, 2) void dist_kernel(
    const unsigned char* __restrict__ x1q, const unsigned char* __restrict__ x2q,
    const float* __restrict__ sq1, const float* __restrict__ sq2,
    float* __restrict__ out) {
  __shared__ __align__(16) char smem[2 * BUFB];  // 51200 B >= 37120 epilogue

  const int tid = threadIdx.x;
  const int wave = tid >> 6, lane = tid & 63;
  const int bid = blockIdx.x;
  const int b = bid & 7;          // batch -> XCD
  const int bm = (bid >> 3) & 7;  // fastest: A streams, B-tile L2-hot
  const int bn = bid >> 6;

  const unsigned char* Ag = x1q + ((size_t)b * N1 + bm * BM) * KD;
  const unsigned char* Bg = x2q + ((size_t)b * N2 + bn * BN) * KD;

  // staging: lane -> (row lr, 16B slot sl), fetch the swizzled global group
  const int lr = lane >> 2, sl = lane & 3;
  const int goff = (sl ^ ((lr >> 1) & 3)) * 16;

  // fragments: lane (fr, quad) reads swizzled slot -> global 16B group `quad`
  const int quad = lane >> 4, fr = lane & 15;
  const int fslot = (fr * 4 + (quad ^ ((fr >> 1) & 3))) * 16;

  f32x4 acc[4][9];
#pragma unroll
  for (int i = 0; i < 4; ++i)
#pragma unroll
    for (int j = 0; j < 9; ++j) {
      f32x4 z = {0.f, 0.f, 0.f, 0.f};
      acc[i][j] = z;
    }

  // stage(k0) into buffer `buf`: 25 chunks (0..15 = A 256 rows, 16..24 = B 144)
  auto stage = [&](int buf, int k0) {
    char* base = smem + buf * BUFB;
    for (int j = wave; j < 25; j += 4) {
      const unsigned char* g;
      if (j < 16)
        g = Ag + (size_t)(j * 16 + lr) * KD + k0 + goff;
      else
        g = Bg + (size_t)((j - 16) * 16 + lr) * KD + k0 + goff;
      async_copy16(g, base + j * 1024 + lane * 16);
    }
  };

  stage(0, 0);  // prologue prefetch
  for (int i = 0; i < 16; ++i) {
    const int cur = i & 1;
    __syncthreads();  // drains cur's loads (issued a full iter ago) + guards nxt reuse
    if (i < 15) stage(cur ^ 1, (i + 1) * 64);
    const char* cb = smem + cur * BUFB;

    i64x2 a[4];
#pragma unroll
    for (int tm = 0; tm < 4; ++tm)
      a[tm] = *(const i64x2*)(cb + (wave * 4 + tm) * 1024 + fslot);
#pragma unroll
    for (int tn = 0; tn < 9; ++tn) {
      i64x2 bf = *(const i64x2*)(cb + 16384 + tn * 1024 + fslot);
#pragma unroll
      for (int tm = 0; tm < 4; ++tm) {
        acc[tm][tn] = __builtin_amdgcn_mfma_f32_16x16x32_fp8_fp8(a[tm].x, bf.x, acc[tm][tn], 0, 0, 0);
        acc[tm][tn] = __builtin_amdgcn_mfma_f32_16x16x32_fp8_fp8(a[tm].y, bf.y, acc[tm][tn], 0, 0, 0);
      }
    }
  }

  // ---- epilogue: d = sq1 + sq2 - 2*cross, min over 9-col groups, sum ----
  float s2[9];
#pragma unroll
  for (int tn = 0; tn < 9; ++tn)
    s2[tn] = sq2[(size_t)b * N2 + bn * BN + tn * 16 + fr];

  float s1v[4][4];
#pragma unroll
  for (int tm = 0; tm < 4; ++tm)
#pragma unroll
    for (int r = 0; r < 4; ++r)
      s1v[tm][r] = sq1[(size_t)b * N1 + bm * BM + wave * 64 + tm * 16 + quad * 4 + r];

  float* eps = (float*)smem;
  float local = 0.f;
#pragma unroll  // FULL unroll: acc indices must be compile-time constants
  for (int tm = 0; tm < 4; ++tm) {
    __syncthreads();  // K-loop LDS / previous chunk fully consumed
    // D layout (16x16x32, dtype-independent): col = lane&15 (x2 row),
    // row = quad*4 + reg (x1 row). Chunk row = wave*16 + quad*4 + r.
#pragma unroll
    for (int tn = 0; tn < 9; ++tn)
#pragma unroll
      for (int r = 0; r < 4; ++r)
        eps[(wave * 16 + quad * 4 + r) * BNP + tn * 16 + fr] =
            s1v[tm][r] + s2[tn] - 2.0f * acc[tm][tn][r];
    __syncthreads();
    // 64 rows x 16 groups = 1024 groups, 4 per thread
#pragma unroll
    for (int qq = 0; qq < 4; ++qq) {
      int g = tid + qq * 256;
      int row = g >> 4, grp = g & 15;
      const float* p = eps + row * BNP + grp * 9;
      float mn = p[0];
#pragma unroll
      for (int jj = 1; jj < 9; ++jj) mn = fminf(mn, p[jj]);
      local += mn;
    }
  }

#pragma unroll
  for (int off = 32; off > 0; off >>= 1) local += __shfl_down(local, off);
  __syncthreads();
  if (lane == 0) eps[wave] = local;
  __syncthreads();
  if (tid == 0) {
    float s = eps[0] + eps[1] + eps[2] + eps[3];
    // total group count = 8 * 2048 * 1152 / 9 = 2097152
    atomicAdd(out, s * (1.0f / 2097152.0f));
  }
}

extern "C" void kernel_launch(void* const* d_in, const int* in_sizes, int n_in,
                              void* d_out, int out_size, void* d_ws, size_t ws_size,
                              hipStream_t stream) {
  const float* x1 = (const float*)d_in[0];
  const float* x2 = (const float*)d_in[1];
  char* ws = (char*)d_ws;
  const size_t x1q_bytes = (size_t)NB * N1 * KD;  // 16777216
  const size_t x2q_bytes = (size_t)NB * N2 * KD;  // 9437184
  unsigned char* x1q = (unsigned char*)ws;
  unsigned char* x2q = (unsigned char*)(ws + x1q_bytes);
  float* sq1 = (float*)(ws + x1q_bytes + x2q_bytes);
  float* sq2 = (float*)(ws + x1q_bytes + x2q_bytes + (size_t)NB * N1 * 4);

  (void)hipMemsetAsync(d_out, 0, sizeof(float), stream);
  convert_kernel<<<NB * (N1 / 4 + N2 / 4), 256, 0, stream>>>(x1, x2, x1q, x2q, sq1, sq2);
  dist_kernel<<<NB * (N1 / BM) * (N2 / BN), 256, 0, stream>>>(x1q, x2q, sq1, sq2,
                                                              (float*)d_out);
}